// Round 10
// baseline (442.140 us; speedup 1.0000x reference)
//
#include <hip/hip_runtime.h>
#include <hip/hip_bf16.h>
#include <stdint.h>

// Problem constants: B=4, S=1024, E=1024, H=16, D=64
// Dtypes (r0-r9 proven): ALL inputs fp32 (mask int32), outputs fp32.
#define BATCH 4
#define SEQ   1024
#define EMB   1024
#define NH    16
#define HD    64

typedef short s8v __attribute__((ext_vector_type(8)));   // 8 bf16 (A/B frag)
typedef float f4v __attribute__((ext_vector_type(4)));   // 4 fp32 (C/D frag)

__device__ __forceinline__ uint16_t f2bf(float f) {
    __hip_bfloat16 h = __float2bfloat16(f);
    return *reinterpret_cast<uint16_t*>(&h);
}
__device__ __forceinline__ short bfraw(float f) {
    __hip_bfloat16 h = __float2bfloat16(f);
    return *reinterpret_cast<short*>(&h);
}
// Load 8 consecutive fp32, pack to 8-wide bf16 fragment.
__device__ __forceinline__ s8v cvt8(const float* p) {
    float4 a = *(const float4*)p;
    float4 b = *(const float4*)(p + 4);
    s8v r;
    r[0] = bfraw(a.x); r[1] = bfraw(a.y); r[2] = bfraw(a.z); r[3] = bfraw(a.w);
    r[4] = bfraw(b.x); r[5] = bfraw(b.y); r[6] = bfraw(b.z); r[7] = bfraw(b.w);
    return r;
}

// Bitpack mask: int32 [B,S,S] -> 1 bit/elem (512 KB).
__global__ __launch_bounds__(256) void pack_mask(
        const int* __restrict__ mask, unsigned long long* __restrict__ Mb64)
{
    const size_t gid = (size_t)blockIdx.x * 256 + threadIdx.x;
    const unsigned long long bal = __ballot(mask[gid] != 0);
    if ((threadIdx.x & 63) == 0) Mb64[gid >> 6] = bal;
}

// Prepass: convert 4 weight matrices + 3 activation inputs fp32->bf16.
__global__ __launch_bounds__(256) void cvt_all(
        const float* __restrict__ W0, const float* __restrict__ W1,
        const float* __restrict__ W2, const float* __restrict__ W3,
        const float* __restrict__ X0, const float* __restrict__ X1,
        const float* __restrict__ X2,
        uint16_t* __restrict__ Wdst, uint16_t* __restrict__ Xq,
        uint16_t* __restrict__ Xk, uint16_t* __restrict__ Xv)
{
    const int y = blockIdx.y;
    const size_t off = ((size_t)blockIdx.x * 256 + threadIdx.x) * 8;
    if (y < 4) {
        if (blockIdx.x >= 512) return;               // W: 1Mi elems
        const float* s = (y == 0) ? W0 : (y == 1) ? W1 : (y == 2) ? W2 : W3;
        *(s8v*)(Wdst + (size_t)y * EMB * EMB + off) = cvt8(s + off);
    } else {
        const float* s = (y == 4) ? X0 : (y == 5) ? X1 : X2;
        uint16_t*    d = (y == 4) ? Xq : (y == 5) ? Xk : Xv;
        *(s8v*)(d + off) = cvt8(s + off);
    }
}

// Triple-GEMM, 128x128 tile, BK=64 (r10).
// KEY FIX (r10): next-tile global loads are issued AFTER the "tile staged"
// __syncthreads. __syncthreads drains vmcnt(0) [guide §5], so r6-r9's
// placement (loads before that barrier) exposed full L2 latency every K-step
// (~300cy x 32 = the reason these GEMMs sat at ~165 TF). Issued after the
// barrier, the loads fly across the ds_read+MFMA phase (~450cy) and drain
// hidden at the NEXT iteration's first barrier. sched_barrier(0) pins the
// load cluster above the compute cluster. BK=64 also halves barrier count
// (16 K-steps) and doubles MFMA per phase (16/wave).
// LDS rows padded to 72 elems (144B): fragment ds_read_b128 rows advance
// 4 banks/row -> 2-way aliasing only (free, m136).
// 512 thr = 8 waves (2m x 4n; wave tile 64x32). __launch_bounds__(512,2).
// scatter==1: bf16 [B,H,S,D]. scatter==2: bf16 [B,H,D,S]. scatter==0: fp32 [M][N].
__global__ __launch_bounds__(512, 2) void gemm3(
        const uint16_t* __restrict__ X0, const uint16_t* __restrict__ W0,
        const float* __restrict__ b0, void* __restrict__ o0, int sc0, float ss0,
        const uint16_t* __restrict__ X1, const uint16_t* __restrict__ W1,
        const float* __restrict__ b1, void* __restrict__ o1, int sc1, float ss1,
        const uint16_t* __restrict__ X2, const uint16_t* __restrict__ W2,
        const float* __restrict__ b2, void* __restrict__ o2, int sc2, float ss2)
{
    __shared__ __attribute__((aligned(16))) uint16_t As[128][72];
    __shared__ __attribute__((aligned(16))) uint16_t Bs[128][72];

    const int z = blockIdx.z;
    const uint16_t* Xb   = (z == 0) ? X0 : (z == 1) ? X1 : X2;
    const uint16_t* Wb   = (z == 0) ? W0 : (z == 1) ? W1 : W2;
    const float*    bias = (z == 0) ? b0 : (z == 1) ? b1 : b2;
    void*           outv = (z == 0) ? o0 : (z == 1) ? o1 : o2;
    const int     scatter = (z == 0) ? sc0 : (z == 1) ? sc1 : sc2;
    const float   scale   = (z == 0) ? ss0 : (z == 1) ? ss1 : ss2;

    const int t    = threadIdx.x;
    const int lane = t & 63;
    const int w    = t >> 6;              // 0..7
    const int wm = w & 1;                 // m half (64 rows)
    const int wn = w >> 1;                // n quarter (32 cols)
    const int m0 = blockIdx.y * 128;
    const int n0 = blockIdx.x * 128;
    const int ar = lane & 15;             // fragment row
    const int aq = lane >> 4;             // quad -> k offset aq*8

    const int srow = t >> 3;              // staging row 0..63 (+64 second half)
    const int scol = (t & 7) * 8;         // staging col group (0..56)

    const uint16_t* gA = Xb + (size_t)(m0 + srow) * EMB + scol;
    const uint16_t* gB = Wb + (size_t)(n0 + srow) * EMB + scol;

    f4v acc[4][2];
    #pragma unroll
    for (int i = 0; i < 4; ++i)
        #pragma unroll
        for (int j = 0; j < 2; ++j) acc[i][j] = (f4v){0.f, 0.f, 0.f, 0.f};

    // prologue: K-tile 0 into regs
    s8v ra0 = *(const s8v*)gA;
    s8v ra1 = *(const s8v*)(gA + 64 * EMB);
    s8v rb0 = *(const s8v*)gB;
    s8v rb1 = *(const s8v*)(gB + 64 * EMB);

    for (int k0 = 0; k0 < EMB; k0 += 64) {
        __syncthreads();                              // (1) readers of prev tile done
        *(s8v*)&As[srow][scol]      = ra0;
        *(s8v*)&As[srow + 64][scol] = ra1;
        *(s8v*)&Bs[srow][scol]      = rb0;
        *(s8v*)&Bs[srow + 64][scol] = rb1;
        __syncthreads();                              // (2) tile staged

        // issue next-tile loads NOW (after barrier: they stay in flight
        // across the compute phase; drained hidden at next (1))
        const int kn = (k0 + 64) & (EMB - 1);         // wrap: last-iter load unused
        ra0 = *(const s8v*)(gA + kn);
        ra1 = *(const s8v*)(gA + 64 * EMB + kn);
        rb0 = *(const s8v*)(gB + kn);
        rb1 = *(const s8v*)(gB + 64 * EMB + kn);
        __builtin_amdgcn_sched_barrier(0);            // pin loads above compute

        #pragma unroll
        for (int kk = 0; kk < 2; ++kk) {
            s8v af[4], bf[2];
            #pragma unroll
            for (int i = 0; i < 4; ++i)
                af[i] = *(const s8v*)&As[wm * 64 + i * 16 + ar][kk * 32 + aq * 8];
            #pragma unroll
            for (int j = 0; j < 2; ++j)
                bf[j] = *(const s8v*)&Bs[wn * 32 + j * 16 + ar][kk * 32 + aq * 8];
            #pragma unroll
            for (int i = 0; i < 4; ++i)
                #pragma unroll
                for (int j = 0; j < 2; ++j)
                    acc[i][j] = __builtin_amdgcn_mfma_f32_16x16x32_bf16(af[i], bf[j], acc[i][j], 0, 0, 0);
        }
    }

    // C/D layout: col = lane&15 (n), row = (lane>>4)*4 + r (m)  [m89]
    #pragma unroll
    for (int i = 0; i < 4; ++i) {
        const int crow = m0 + wm * 64 + i * 16 + aq * 4;
        #pragma unroll
        for (int j = 0; j < 2; ++j) {
            const int n = n0 + wn * 32 + j * 16 + ar;
            const float bv = bias[n];
            #pragma unroll
            for (int r = 0; r < 4; ++r) {
                const int m = crow + r;
                const float v = (acc[i][j][r] + bv) * scale;
                if (scatter == 1) {
                    size_t idx = (size_t)(((m >> 10) * NH + (n >> 6)) * SEQ + (m & 1023)) * HD + (n & 63);
                    ((uint16_t*)outv)[idx] = f2bf(v);
                } else if (scatter == 2) {
                    size_t idx = (size_t)(((m >> 10) * NH + (n >> 6)) * HD + (n & 63)) * SEQ + (m & 1023);
                    ((uint16_t*)outv)[idx] = f2bf(v);
                } else {
                    ((float*)outv)[(size_t)m * EMB + n] = v;
                }
            }
        }
    }
}

// Flash ctx (r10): single-stream, one-chunk-ahead register prefetch PINNED
// with __builtin_amdgcn_sched_barrier(0) -- a hard compile-time fence the
// register-minimizing scheduler cannot undo (r6's plain prefetch and r9's
// dual-stream were both re-sunk: VGPR_Count stayed 52/64, chains serialized).
// Manual 2x unroll with swapped K/V buffers avoids rotation copies.
// One wave owns one (b,h,16-q) tile, streams all 1024 k (32 chunks of 32).
// No-max softmax (Q pre-scaled 1/8; masked -> exact 0), O/l normalized at end.
// Zero __syncthreads after mask stage. Grid 1024; XCD swizzle keeps each
// (b,h)'s K/V L2-resident. ~112 live regs < 128 bucket (watch FETCH for spill).
__global__ __launch_bounds__(256, 4) void flash_ctx(
        const uint16_t* __restrict__ Qb, const uint16_t* __restrict__ Kb,
        const uint16_t* __restrict__ Vt, const uint32_t* __restrict__ Mb,
        uint16_t* __restrict__ ctx, float* __restrict__ linv_out)
{
    __shared__ uint32_t Ml[4][16][33];                              // mask bits
    __shared__ __attribute__((aligned(16))) uint16_t Pt[4][16][56]; // P^T

    const int t = threadIdx.x;
    const int w = t >> 6, lane = t & 63;
    const int ar = lane & 15, aq = lane >> 4;

    const int id   = blockIdx.x;            // 0..1023
    const int xcd  = id & 7;
    const int rest = id >> 3;               // 0..127
    const int bh   = xcd * 8 + (rest & 7);  // same (b,h) -> same XCD
    const int qt   = (rest >> 3) * 4 + w;   // 0..63, per-wave
    const int b = bh >> 4, h = bh & 15;
    const size_t hb = ((size_t)(b * NH + h)) * SEQ * HD;

    // stage this wave's 16 q-rows of mask bits (512 u32, coalesced)
    {
        const uint32_t* src = Mb + (((size_t)b * SEQ + qt * 16) << 5);
        uint4 m0 = *(const uint4*)(src + lane * 8);
        uint4 m1 = *(const uint4*)(src + lane * 8 + 4);
        const int pr = (lane * 8) >> 5, pc = (lane * 8) & 31;
        Ml[w][pr][pc + 0] = m0.x; Ml[w][pr][pc + 1] = m0.y;
        Ml[w][pr][pc + 2] = m0.z; Ml[w][pr][pc + 3] = m0.w;
        Ml[w][pr][pc + 4] = m1.x; Ml[w][pr][pc + 5] = m1.y;
        Ml[w][pr][pc + 6] = m1.z; Ml[w][pr][pc + 7] = m1.w;
    }

    const uint16_t* qp = Qb + hb + (size_t)(qt * 16 + ar) * HD + aq * 8;
    const s8v a0 = *(const s8v*)qp;
    const s8v a1 = *(const s8v*)(qp + 32);

    const uint16_t* kbase = Kb + hb + (size_t)ar * HD + aq * 8;
    const uint16_t* vbase = Vt + hb + (size_t)ar * SEQ + aq * 8;

    f4v O0 = {0.f,0.f,0.f,0.f}, O1 = O0, O2 = O0, O3 = O0;
    float lsum[4] = {0.f, 0.f, 0.f, 0.f};

    // chunk body: prefetch chunk ci+1 into nxt*, compute chunk ci from cur*.
    auto body = [&](int ci, s8v* curK, s8v* curV, s8v* nxtK, s8v* nxtV) {
        const int kcn = ((ci + 1) & 31) * 32;
        const uint16_t* kn = kbase + (size_t)kcn * HD;
        const uint16_t* vn = vbase + kcn;
        nxtK[0] = *(const s8v*)kn;
        nxtK[1] = *(const s8v*)(kn + 32);
        nxtK[2] = *(const s8v*)(kn + 16 * HD);
        nxtK[3] = *(const s8v*)(kn + 16 * HD + 32);
        nxtV[0] = *(const s8v*)vn;
        nxtV[1] = *(const s8v*)(vn + 16 * SEQ);
        nxtV[2] = *(const s8v*)(vn + 32 * SEQ);
        nxtV[3] = *(const s8v*)(vn + 48 * SEQ);
        __builtin_amdgcn_sched_barrier(0);  // loads stay above compute

        // ---- QK^T (2 tiles: k = kc+ar, kc+16+ar) ----
        f4v z = {0.f,0.f,0.f,0.f};
        f4v s0 = __builtin_amdgcn_mfma_f32_16x16x32_bf16(a0, curK[0], z, 0, 0, 0);
        s0 = __builtin_amdgcn_mfma_f32_16x16x32_bf16(a1, curK[1], s0, 0, 0, 0);
        f4v s1 = __builtin_amdgcn_mfma_f32_16x16x32_bf16(a0, curK[2], z, 0, 0, 0);
        s1 = __builtin_amdgcn_mfma_f32_16x16x32_bf16(a1, curK[3], s1, 0, 0, 0);

        // ---- mask + exp + transpose into per-wave LDS ----
        #pragma unroll
        for (int r = 0; r < 4; ++r) {
            const uint32_t mw = Ml[w][aq * 4 + r][ci];
            const float e0 = ((mw >> ar) & 1u)        ? __expf(s0[r]) : 0.f;
            const float e1 = ((mw >> (16 + ar)) & 1u) ? __expf(s1[r]) : 0.f;
            lsum[r] += e0 + e1;
            Pt[w][aq * 4 + r][ar]      = f2bf(e0);
            Pt[w][aq * 4 + r][16 + ar] = f2bf(e1);
        }

        // ---- PV: A = P^T-read (lane ar = q, k = aq*8..), B = Vt rows ----
        const s8v pa = *(const s8v*)&Pt[w][ar][aq * 8];
        O0 = __builtin_amdgcn_mfma_f32_16x16x32_bf16(pa, curV[0], O0, 0, 0, 0);
        O1 = __builtin_amdgcn_mfma_f32_16x16x32_bf16(pa, curV[1], O1, 0, 0, 0);
        O2 = __builtin_amdgcn_mfma_f32_16x16x32_bf16(pa, curV[2], O2, 0, 0, 0);
        O3 = __builtin_amdgcn_mfma_f32_16x16x32_bf16(pa, curV[3], O3, 0, 0, 0);
    };

    s8v KA[4], VA[4], KB[4], VB[4];
    // prologue: chunk 0 into KA/VA
    KA[0] = *(const s8v*)kbase;
    KA[1] = *(const s8v*)(kbase + 32);
    KA[2] = *(const s8v*)(kbase + 16 * HD);
    KA[3] = *(const s8v*)(kbase + 16 * HD + 32);
    VA[0] = *(const s8v*)vbase;
    VA[1] = *(const s8v*)(vbase + 16 * SEQ);
    VA[2] = *(const s8v*)(vbase + 32 * SEQ);
    VA[3] = *(const s8v*)(vbase + 48 * SEQ);

    for (int ci = 0; ci < 32; ci += 2) {
        body(ci,     KA, VA, KB, VB);   // compute A-buf, prefetch into B-buf
        body(ci + 1, KB, VB, KA, VA);   // compute B-buf, prefetch into A-buf
    }

    // ---- row sums: reduce over the 16 ar-lanes (aq group preserved) ----
    #pragma unroll
    for (int off = 1; off < 16; off <<= 1) {
        #pragma unroll
        for (int r = 0; r < 4; ++r) lsum[r] += __shfl_xor(lsum[r], off);
    }
    float inv[4];
    #pragma unroll
    for (int r = 0; r < 4; ++r) inv[r] = 1.0f / lsum[r];

    // ---- store ctx (bf16 [B,S,H,D]) and 1/l ----
    #pragma unroll
    for (int r = 0; r < 4; ++r) {
        const int q = qt * 16 + aq * 4 + r;
        uint16_t* cp = ctx + ((size_t)(b * SEQ + q) * NH + h) * HD + ar;
        cp[ 0] = f2bf(O0[r] * inv[r]);
        cp[16] = f2bf(O1[r] * inv[r]);
        cp[32] = f2bf(O2[r] * inv[r]);
        cp[48] = f2bf(O3[r] * inv[r]);
    }
    if (ar == 0) {
        #pragma unroll
        for (int r = 0; r < 4; ++r)
            linv_out[(size_t)(b * NH + h) * SEQ + qt * 16 + aq * 4 + r] = inv[r];
    }
}

// attn_avg: recompute QK^T, apply exp * (1/l) * (1/16), sum over ALL 16 heads
// in regs, write FINAL attn_out. Block (qt, b*4+kq), 8 waves, wave w owns k in
// [kq*256 + w*32, +32). Grid 1024. No barriers, no LDS. (r8 version, proven.)
__global__ __launch_bounds__(512, 4) void attn_avg(
        const uint16_t* __restrict__ Qb, const uint16_t* __restrict__ Kb,
        const uint32_t* __restrict__ Mb, const float* __restrict__ linv,
        float* __restrict__ attn_out)
{
    const int qt = blockIdx.x;
    const int b  = blockIdx.y >> 2;
    const int kq = blockIdx.y & 3;
    const int t = threadIdx.x;
    const int w = t >> 6, lane = t & 63;
    const int ar = lane & 15, aq = lane >> 4;
    const int k0 = kq * 256 + w * 32;

    uint32_t mw[4];
    #pragma unroll
    for (int r = 0; r < 4; ++r)
        mw[r] = Mb[(((size_t)b * SEQ + qt * 16 + aq * 4 + r) << 5) + (k0 >> 5)];

    float acc[8];
    #pragma unroll
    for (int j = 0; j < 8; ++j) acc[j] = 0.f;

    for (int h = 0; h < NH; ++h) {
        const size_t hb = ((size_t)(b * NH + h)) * SEQ * HD;
        const uint16_t* qp = Qb + hb + (size_t)(qt * 16 + ar) * HD + aq * 8;
        const s8v a0 = *(const s8v*)qp;
        const s8v a1 = *(const s8v*)(qp + 32);
        float fs[4];
        #pragma unroll
        for (int r = 0; r < 4; ++r)
            fs[r] = linv[(size_t)(b * NH + h) * SEQ + qt * 16 + aq * 4 + r] * 0.0625f;

        #pragma unroll
        for (int nt = 0; nt < 2; ++nt) {
            const uint16_t* kp = Kb + hb + (size_t)(k0 + nt * 16 + ar) * HD + aq * 8;
            s8v bl = *(const s8v*)kp, bh2 = *(const s8v*)(kp + 32);
            f4v z = {0.f,0.f,0.f,0.f};
            f4v s = __builtin_amdgcn_mfma_f32_16x16x32_bf16(a0, bl, z, 0, 0, 0);
            s = __builtin_amdgcn_mfma_f32_16x16x32_bf16(a1, bh2, s, 0, 0, 0);
            #pragma unroll
            for (int r = 0; r < 4; ++r) {
                const int bit = nt * 16 + ar;
                if ((mw[r] >> bit) & 1u) acc[r * 2 + nt] += __expf(s[r]) * fs[r];
            }
        }
    }

    #pragma unroll
    for (int r = 0; r < 4; ++r) {
        float* ap = attn_out + ((size_t)b * SEQ + qt * 16 + aq * 4 + r) * SEQ + k0 + ar;
        #pragma unroll
        for (int nt = 0; nt < 2; ++nt) ap[nt * 16] = acc[r * 2 + nt];
    }
}

extern "C" void kernel_launch(void* const* d_in, const int* in_sizes, int n_in,
                              void* d_out, int out_size, void* d_ws, size_t ws_size,
                              hipStream_t stream) {
    const float* q_in = (const float*)d_in[0];
    const float* k_in = (const float*)d_in[1];
    const float* v_in = (const float*)d_in[2];
    const int*   mask = (const int*)d_in[3];
    const float* Wq = (const float*)d_in[4];
    const float* bq = (const float*)d_in[5];
    const float* Wk = (const float*)d_in[6];
    const float* bk = (const float*)d_in[7];
    const float* Wv = (const float*)d_in[8];
    const float* bv = (const float*)d_in[9];
    const float* Wo = (const float*)d_in[10];
    const float* bo = (const float*)d_in[11];

    float* out      = (float*)d_out;                         // [B,S,E] fp32
    float* attn_out = out + (size_t)BATCH * SEQ * EMB;       // [B,S,S] fp32

    const size_t qkv_elems = (size_t)BATCH * NH * SEQ * HD;  // 4 Mi
    uint16_t* Qb  = (uint16_t*)d_ws;                         // [B,H,S,D] bf16 (pre-scaled 1/8)
    uint16_t* Kb  = Qb + qkv_elems;                          // [B,H,S,D] bf16
    uint16_t* Vt  = Kb + qkv_elems;                          // [B,H,D,S] bf16 (transposed!)
    uint16_t* ctx = Vt + qkv_elems;                          // [B,S,E] bf16
    uint16_t* Wcb = ctx + (size_t)BATCH * SEQ * EMB;         // 4x [E,E] bf16 (8 MB)
    uint16_t* Wqb = Wcb;
    uint16_t* Wkb = Wcb + (size_t)EMB * EMB;
    uint16_t* Wvb = Wcb + 2 * (size_t)EMB * EMB;
    uint16_t* Wob = Wcb + 3 * (size_t)EMB * EMB;
    uint16_t* Xq  = Wcb + 4 * (size_t)EMB * EMB;             // [B,S,E] bf16 (8 MB)
    uint16_t* Xk  = Xq + qkv_elems;                          // [B,S,E] bf16 (8 MB)
    uint16_t* Xv  = ctx;   // alias: Xv consumed by V-proj BEFORE attn writes ctx
    uint32_t* Mb32 = (uint32_t*)(Xk + qkv_elems);            // bitpacked mask (512 KB)
    float*    linv = (float*)(Mb32 + (size_t)BATCH * SEQ * 32); // [B,H,S] 1/l (256 KB)

    // prepasses: mask bitpack + all fp32->bf16 conversions
    pack_mask<<<dim3((BATCH * SEQ * SEQ) / 256), 256, 0, stream>>>(
        mask, (unsigned long long*)Mb32);
    cvt_all<<<dim3(2048, 7), 256, 0, stream>>>(Wq, Wk, Wv, Wo, q_in, k_in, v_in,
                                               Wcb, Xq, Xk, Xv);

    // fused QKV projections: one dispatch, 128^2 tiles, BK=64
    dim3 g3(EMB / 128, (BATCH * SEQ) / 128, 3);
    gemm3<<<g3, 512, 0, stream>>>(
        Xq, Wqb, bq, Qb, 1, 0.125f,
        Xk, Wkb, bk, Kb, 1, 1.0f,
        Xv, Wvb, bv, Vt, 2, 1.0f);

    // pinned-prefetch flash ctx, then head-summed attn_avg
    flash_ctx<<<dim3(1024), 256, 0, stream>>>(Qb, Kb, Vt, Mb32, ctx, linv);
    attn_avg<<<dim3(SEQ / 16, BATCH * 4), 512, 0, stream>>>(Qb, Kb, Mb32, linv, attn_out);

    // O projection (same kernel, z-grid of 1)
    dim3 g1(EMB / 128, (BATCH * SEQ) / 128, 1);
    gemm3<<<g1, 512, 0, stream>>>(
        ctx, Wob, bo, out, 0, 1.0f,
        ctx, Wob, bo, out, 0, 1.0f,
        ctx, Wob, bo, out, 0, 1.0f);
}

// Round 12
// 407.067 us; speedup vs baseline: 1.0862x; 1.0862x over previous
//
#include <hip/hip_runtime.h>
#include <hip/hip_bf16.h>
#include <stdint.h>

// Problem constants: B=4, S=1024, E=1024, H=16, D=64
// Dtypes (r0-r9 proven): ALL inputs fp32 (mask int32), outputs fp32.
#define BATCH 4
#define SEQ   1024
#define EMB   1024
#define NH    16
#define HD    64

typedef short s8v __attribute__((ext_vector_type(8)));   // 8 bf16 (A/B frag)
typedef float f4v __attribute__((ext_vector_type(4)));   // 4 fp32 (C/D frag)

__device__ __forceinline__ uint16_t f2bf(float f) {
    __hip_bfloat16 h = __float2bfloat16(f);
    return *reinterpret_cast<uint16_t*>(&h);
}
__device__ __forceinline__ short bfraw(float f) {
    __hip_bfloat16 h = __float2bfloat16(f);
    return *reinterpret_cast<short*>(&h);
}
// Load 8 consecutive fp32, pack to 8-wide bf16 fragment.
__device__ __forceinline__ s8v cvt8(const float* p) {
    float4 a = *(const float4*)p;
    float4 b = *(const float4*)(p + 4);
    s8v r;
    r[0] = bfraw(a.x); r[1] = bfraw(a.y); r[2] = bfraw(a.z); r[3] = bfraw(a.w);
    r[4] = bfraw(b.x); r[5] = bfraw(b.y); r[6] = bfraw(b.z); r[7] = bfraw(b.w);
    return r;
}

// Bitpack mask: int32 [B,S,S] -> 1 bit/elem (512 KB).
__global__ __launch_bounds__(256) void pack_mask(
        const int* __restrict__ mask, unsigned long long* __restrict__ Mb64)
{
    const size_t gid = (size_t)blockIdx.x * 256 + threadIdx.x;
    const unsigned long long bal = __ballot(mask[gid] != 0);
    if ((threadIdx.x & 63) == 0) Mb64[gid >> 6] = bal;
}

// Prepass: convert 4 weight matrices + 3 activation inputs fp32->bf16.
__global__ __launch_bounds__(256) void cvt_all(
        const float* __restrict__ W0, const float* __restrict__ W1,
        const float* __restrict__ W2, const float* __restrict__ W3,
        const float* __restrict__ X0, const float* __restrict__ X1,
        const float* __restrict__ X2,
        uint16_t* __restrict__ Wdst, uint16_t* __restrict__ Xq,
        uint16_t* __restrict__ Xk, uint16_t* __restrict__ Xv)
{
    const int y = blockIdx.y;
    const size_t off = ((size_t)blockIdx.x * 256 + threadIdx.x) * 8;
    if (y < 4) {
        if (blockIdx.x >= 512) return;               // W: 1Mi elems
        const float* s = (y == 0) ? W0 : (y == 1) ? W1 : (y == 2) ? W2 : W3;
        *(s8v*)(Wdst + (size_t)y * EMB * EMB + off) = cvt8(s + off);
    } else {
        const float* s = (y == 4) ? X0 : (y == 5) ? X1 : X2;
        uint16_t*    d = (y == 4) ? Xq : (y == 5) ? Xk : Xv;
        *(s8v*)(d + off) = cvt8(s + off);
    }
}

// Triple-GEMM (r12): 128x128 tile, BK=32, DOUBLE-BUFFERED LDS, ONE barrier
// per K-step, plain reg-staging (r11's global_load_lds suspected in the
// container failure -- removed).
// Schedule per step: {ds_write buf[k&1]; barrier; issue loads k+1; compute
// buf[k&1]}. The loads fly across the ~450cy ds_read+MFMA phase and are
// drained at the NEXT iteration's ds_write -- not at a barrier (the r6-r9
// structure drained vmcnt(0) at the staged-barrier before compute, exposing
// ~300cy x 32 steps: the ~165 TF wall). Race-safe with one barrier: readers
// of buf[c] sit between barrier_k and barrier_{k+1}; the next write of
// buf[c] is after barrier_{k+1}.
// sched_barrier(0) pins the 2 prefetch loads (16 VGPRs, ~90-reg live set --
// ample headroom, unlike flash's r10 pin that spilled a 64-reg acc).
// 512 thr = 8 waves (2m x 4n; wave tile 64x32 -> 8 MFMA : 6 ds_read).
// LDS 2x[128][40]x2 arrays = 40 KB -> 4 blocks/CU at 512 thr. Rows padded
// to 40 elems (80 B, r8-proven bank layout).
// blockIdx.z picks the projection (QKV fused in one dispatch).
// scatter==1: bf16 [B,H,S,D]. scatter==2: bf16 [B,H,D,S]. scatter==0: fp32 [M][N].
__global__ __launch_bounds__(512, 2) void gemm3(
        const uint16_t* __restrict__ X0, const uint16_t* __restrict__ W0,
        const float* __restrict__ b0, void* __restrict__ o0, int sc0, float ss0,
        const uint16_t* __restrict__ X1, const uint16_t* __restrict__ W1,
        const float* __restrict__ b1, void* __restrict__ o1, int sc1, float ss1,
        const uint16_t* __restrict__ X2, const uint16_t* __restrict__ W2,
        const float* __restrict__ b2, void* __restrict__ o2, int sc2, float ss2)
{
    __shared__ __attribute__((aligned(16))) uint16_t As[2][128][40];
    __shared__ __attribute__((aligned(16))) uint16_t Bs[2][128][40];

    const int z = blockIdx.z;
    const uint16_t* Xb   = (z == 0) ? X0 : (z == 1) ? X1 : X2;
    const uint16_t* Wb   = (z == 0) ? W0 : (z == 1) ? W1 : W2;
    const float*    bias = (z == 0) ? b0 : (z == 1) ? b1 : b2;
    void*           outv = (z == 0) ? o0 : (z == 1) ? o1 : o2;
    const int     scatter = (z == 0) ? sc0 : (z == 1) ? sc1 : sc2;
    const float   scale   = (z == 0) ? ss0 : (z == 1) ? ss1 : ss2;

    const int t    = threadIdx.x;
    const int lane = t & 63;
    const int w    = t >> 6;              // 0..7
    const int wm = w & 1;                 // m half (64 rows)
    const int wn = w >> 1;                // n quarter (32 cols)
    const int m0 = blockIdx.y * 128;
    const int n0 = blockIdx.x * 128;
    const int ar = lane & 15;             // fragment row
    const int aq = lane >> 4;             // quad -> k offset aq*8

    const int srow = t >> 2;              // staging row 0..127
    const int scol = (t & 3) * 8;         // staging col group

    const uint16_t* gA = Xb + (size_t)(m0 + srow) * EMB + scol;
    const uint16_t* gB = Wb + (size_t)(n0 + srow) * EMB + scol;

    f4v acc[4][2];
    #pragma unroll
    for (int i = 0; i < 4; ++i)
        #pragma unroll
        for (int j = 0; j < 2; ++j) acc[i][j] = (f4v){0.f, 0.f, 0.f, 0.f};

    // prologue: tile 0 into regs
    s8v ra = *(const s8v*)gA;
    s8v rb = *(const s8v*)gB;

    for (int ki = 0; ki < 32; ++ki) {
        const int cur = ki & 1;
        *(s8v*)&As[cur][srow][scol] = ra;   // implicit vmcnt wait (post-compute)
        *(s8v*)&Bs[cur][srow][scol] = rb;
        __syncthreads();                    // buf[cur] staged; vmcnt already 0

        if (ki + 1 < 32) {                  // issue next-tile loads NOW:
            const int kn = (ki + 1) * 32;   // in flight across the compute
            ra = *(const s8v*)(gA + kn);    // phase, drained at next ds_write
            rb = *(const s8v*)(gB + kn);
        }
        __builtin_amdgcn_sched_barrier(0);  // keep loads above compute

        s8v af[4], bf[2];
        #pragma unroll
        for (int i = 0; i < 4; ++i)
            af[i] = *(const s8v*)&As[cur][wm * 64 + i * 16 + ar][aq * 8];
        #pragma unroll
        for (int j = 0; j < 2; ++j)
            bf[j] = *(const s8v*)&Bs[cur][wn * 32 + j * 16 + ar][aq * 8];
        #pragma unroll
        for (int i = 0; i < 4; ++i)
            #pragma unroll
            for (int j = 0; j < 2; ++j)
                acc[i][j] = __builtin_amdgcn_mfma_f32_16x16x32_bf16(af[i], bf[j], acc[i][j], 0, 0, 0);
    }

    // C/D layout: col = lane&15 (n), row = (lane>>4)*4 + r (m)  [m89]
    #pragma unroll
    for (int i = 0; i < 4; ++i) {
        const int crow = m0 + wm * 64 + i * 16 + aq * 4;
        #pragma unroll
        for (int j = 0; j < 2; ++j) {
            const int n = n0 + wn * 32 + j * 16 + ar;
            const float bv = bias[n];
            #pragma unroll
            for (int r = 0; r < 4; ++r) {
                const int m = crow + r;
                const float v = (acc[i][j][r] + bv) * scale;
                if (scatter == 1) {
                    size_t idx = (size_t)(((m >> 10) * NH + (n >> 6)) * SEQ + (m & 1023)) * HD + (n & 63);
                    ((uint16_t*)outv)[idx] = f2bf(v);
                } else if (scatter == 2) {
                    size_t idx = (size_t)(((m >> 10) * NH + (n >> 6)) * HD + (n & 63)) * SEQ + (m & 1023);
                    ((uint16_t*)outv)[idx] = f2bf(v);
                } else {
                    ((float*)outv)[(size_t)m * EMB + n] = v;
                }
            }
        }
    }
}

// Flash ctx: r9 version VERBATIM (122 us, proven local optimum; benched clean).
__global__ __launch_bounds__(256, 4) void flash_ctx(
        const uint16_t* __restrict__ Qb, const uint16_t* __restrict__ Kb,
        const uint16_t* __restrict__ Vt, const uint32_t* __restrict__ Mb,
        uint16_t* __restrict__ ctx, float* __restrict__ linv_out)
{
    __shared__ uint32_t Ml[4][16][33];                                 // mask bits
    __shared__ __attribute__((aligned(16))) uint16_t Pt[4][2][16][56]; // P^T, per stream

    const int t = threadIdx.x;
    const int w = t >> 6, lane = t & 63;
    const int ar = lane & 15, aq = lane >> 4;

    const int id   = blockIdx.x;            // 0..1023
    const int xcd  = id & 7;
    const int rest = id >> 3;               // 0..127
    const int bh   = xcd * 8 + (rest & 7);  // same (b,h) -> same XCD
    const int qt   = (rest >> 3) * 4 + w;   // 0..63, per-wave
    const int b = bh >> 4, h = bh & 15;
    const size_t hb = ((size_t)(b * NH + h)) * SEQ * HD;

    // stage this wave's 16 q-rows of mask bits (512 u32, coalesced)
    {
        const uint32_t* src = Mb + (((size_t)b * SEQ + qt * 16) << 5);
        uint4 m0 = *(const uint4*)(src + lane * 8);
        uint4 m1 = *(const uint4*)(src + lane * 8 + 4);
        const int pr = (lane * 8) >> 5, pc = (lane * 8) & 31;
        Ml[w][pr][pc + 0] = m0.x; Ml[w][pr][pc + 1] = m0.y;
        Ml[w][pr][pc + 2] = m0.z; Ml[w][pr][pc + 3] = m0.w;
        Ml[w][pr][pc + 4] = m1.x; Ml[w][pr][pc + 5] = m1.y;
        Ml[w][pr][pc + 6] = m1.z; Ml[w][pr][pc + 7] = m1.w;
    }

    const uint16_t* qp = Qb + hb + (size_t)(qt * 16 + ar) * HD + aq * 8;
    const s8v a0 = *(const s8v*)qp;
    const s8v a1 = *(const s8v*)(qp + 32);

    const uint16_t* kbase = Kb + hb + (size_t)ar * HD + aq * 8;
    const uint16_t* vbase = Vt + hb + (size_t)ar * SEQ + aq * 8;

    f4v OA0 = {0.f,0.f,0.f,0.f}, OA1 = OA0, OA2 = OA0, OA3 = OA0;
    f4v OB0 = OA0, OB1 = OA0, OB2 = OA0, OB3 = OA0;
    float lsA[4] = {0.f, 0.f, 0.f, 0.f};
    float lsB[4] = {0.f, 0.f, 0.f, 0.f};

    for (int ci = 0; ci < 16; ++ci) {
        const int cA = ci * 2, cB = ci * 2 + 1;
        const int kcA = cA * 32, kcB = cB * 32;

        const uint16_t* kA = kbase + (size_t)kcA * HD;
        const uint16_t* kB = kbase + (size_t)kcB * HD;
        s8v Abl0 = *(const s8v*)kA,            Abh0 = *(const s8v*)(kA + 32);
        s8v Abl1 = *(const s8v*)(kA + 16*HD),  Abh1 = *(const s8v*)(kA + 16*HD + 32);
        s8v Bbl0 = *(const s8v*)kB,            Bbh0 = *(const s8v*)(kB + 32);
        s8v Bbl1 = *(const s8v*)(kB + 16*HD),  Bbh1 = *(const s8v*)(kB + 16*HD + 32);

        f4v z = {0.f,0.f,0.f,0.f};
        f4v sA0 = __builtin_amdgcn_mfma_f32_16x16x32_bf16(a0, Abl0, z, 0, 0, 0);
        sA0 = __builtin_amdgcn_mfma_f32_16x16x32_bf16(a1, Abh0, sA0, 0, 0, 0);
        f4v sA1 = __builtin_amdgcn_mfma_f32_16x16x32_bf16(a0, Abl1, z, 0, 0, 0);
        sA1 = __builtin_amdgcn_mfma_f32_16x16x32_bf16(a1, Abh1, sA1, 0, 0, 0);
        f4v sB0 = __builtin_amdgcn_mfma_f32_16x16x32_bf16(a0, Bbl0, z, 0, 0, 0);
        sB0 = __builtin_amdgcn_mfma_f32_16x16x32_bf16(a1, Bbh0, sB0, 0, 0, 0);
        f4v sB1 = __builtin_amdgcn_mfma_f32_16x16x32_bf16(a0, Bbl1, z, 0, 0, 0);
        sB1 = __builtin_amdgcn_mfma_f32_16x16x32_bf16(a1, Bbh1, sB1, 0, 0, 0);

        const uint16_t* vA = vbase + kcA;
        const uint16_t* vB = vbase + kcB;
        s8v Av0 = *(const s8v*)(vA);
        s8v Av1 = *(const s8v*)(vA + 16 * SEQ);
        s8v Av2 = *(const s8v*)(vA + 32 * SEQ);
        s8v Av3 = *(const s8v*)(vA + 48 * SEQ);
        s8v Bv0 = *(const s8v*)(vB);
        s8v Bv1 = *(const s8v*)(vB + 16 * SEQ);
        s8v Bv2 = *(const s8v*)(vB + 32 * SEQ);
        s8v Bv3 = *(const s8v*)(vB + 48 * SEQ);

        #pragma unroll
        for (int r = 0; r < 4; ++r) {
            const uint32_t mwA = Ml[w][aq * 4 + r][cA];
            const float e0 = ((mwA >> ar) & 1u)        ? __expf(sA0[r]) : 0.f;
            const float e1 = ((mwA >> (16 + ar)) & 1u) ? __expf(sA1[r]) : 0.f;
            lsA[r] += e0 + e1;
            Pt[w][0][aq * 4 + r][ar]      = f2bf(e0);
            Pt[w][0][aq * 4 + r][16 + ar] = f2bf(e1);
        }
        #pragma unroll
        for (int r = 0; r < 4; ++r) {
            const uint32_t mwB = Ml[w][aq * 4 + r][cB];
            const float e0 = ((mwB >> ar) & 1u)        ? __expf(sB0[r]) : 0.f;
            const float e1 = ((mwB >> (16 + ar)) & 1u) ? __expf(sB1[r]) : 0.f;
            lsB[r] += e0 + e1;
            Pt[w][1][aq * 4 + r][ar]      = f2bf(e0);
            Pt[w][1][aq * 4 + r][16 + ar] = f2bf(e1);
        }

        const s8v paA = *(const s8v*)&Pt[w][0][ar][aq * 8];
        OA0 = __builtin_amdgcn_mfma_f32_16x16x32_bf16(paA, Av0, OA0, 0, 0, 0);
        OA1 = __builtin_amdgcn_mfma_f32_16x16x32_bf16(paA, Av1, OA1, 0, 0, 0);
        OA2 = __builtin_amdgcn_mfma_f32_16x16x32_bf16(paA, Av2, OA2, 0, 0, 0);
        OA3 = __builtin_amdgcn_mfma_f32_16x16x32_bf16(paA, Av3, OA3, 0, 0, 0);
        const s8v paB = *(const s8v*)&Pt[w][1][ar][aq * 8];
        OB0 = __builtin_amdgcn_mfma_f32_16x16x32_bf16(paB, Bv0, OB0, 0, 0, 0);
        OB1 = __builtin_amdgcn_mfma_f32_16x16x32_bf16(paB, Bv1, OB1, 0, 0, 0);
        OB2 = __builtin_amdgcn_mfma_f32_16x16x32_bf16(paB, Bv2, OB2, 0, 0, 0);
        OB3 = __builtin_amdgcn_mfma_f32_16x16x32_bf16(paB, Bv3, OB3, 0, 0, 0);
    }

    float lsum[4];
    #pragma unroll
    for (int r = 0; r < 4; ++r) {
        OA0[r] += OB0[r]; OA1[r] += OB1[r];
        OA2[r] += OB2[r]; OA3[r] += OB3[r];
        lsum[r] = lsA[r] + lsB[r];
    }

    #pragma unroll
    for (int off = 1; off < 16; off <<= 1) {
        #pragma unroll
        for (int r = 0; r < 4; ++r) lsum[r] += __shfl_xor(lsum[r], off);
    }
    float inv[4];
    #pragma unroll
    for (int r = 0; r < 4; ++r) inv[r] = 1.0f / lsum[r];

    #pragma unroll
    for (int r = 0; r < 4; ++r) {
        const int q = qt * 16 + aq * 4 + r;
        uint16_t* cp = ctx + ((size_t)(b * SEQ + q) * NH + h) * HD + ar;
        cp[ 0] = f2bf(OA0[r] * inv[r]);
        cp[16] = f2bf(OA1[r] * inv[r]);
        cp[32] = f2bf(OA2[r] * inv[r]);
        cp[48] = f2bf(OA3[r] * inv[r]);
    }
    if (ar == 0) {
        #pragma unroll
        for (int r = 0; r < 4; ++r)
            linv_out[(size_t)(b * NH + h) * SEQ + qt * 16 + aq * 4 + r] = inv[r];
    }
}

// attn_avg: recompute QK^T, apply exp * (1/l) * (1/16), sum over ALL 16 heads
// in regs, write FINAL attn_out. Block (qt, b*4+kq), 8 waves, wave w owns k in
// [kq*256 + w*32, +32). Grid 1024. No barriers, no LDS. (r8 version, proven.)
__global__ __launch_bounds__(512, 4) void attn_avg(
        const uint16_t* __restrict__ Qb, const uint16_t* __restrict__ Kb,
        const uint32_t* __restrict__ Mb, const float* __restrict__ linv,
        float* __restrict__ attn_out)
{
    const int qt = blockIdx.x;
    const int b  = blockIdx.y >> 2;
    const int kq = blockIdx.y & 3;
    const int t = threadIdx.x;
    const int w = t >> 6, lane = t & 63;
    const int ar = lane & 15, aq = lane >> 4;
    const int k0 = kq * 256 + w * 32;

    uint32_t mw[4];
    #pragma unroll
    for (int r = 0; r < 4; ++r)
        mw[r] = Mb[(((size_t)b * SEQ + qt * 16 + aq * 4 + r) << 5) + (k0 >> 5)];

    float acc[8];
    #pragma unroll
    for (int j = 0; j < 8; ++j) acc[j] = 0.f;

    for (int h = 0; h < NH; ++h) {
        const size_t hb = ((size_t)(b * NH + h)) * SEQ * HD;
        const uint16_t* qp = Qb + hb + (size_t)(qt * 16 + ar) * HD + aq * 8;
        const s8v a0 = *(const s8v*)qp;
        const s8v a1 = *(const s8v*)(qp + 32);
        float fs[4];
        #pragma unroll
        for (int r = 0; r < 4; ++r)
            fs[r] = linv[(size_t)(b * NH + h) * SEQ + qt * 16 + aq * 4 + r] * 0.0625f;

        #pragma unroll
        for (int nt = 0; nt < 2; ++nt) {
            const uint16_t* kp = Kb + hb + (size_t)(k0 + nt * 16 + ar) * HD + aq * 8;
            s8v bl = *(const s8v*)kp, bh2 = *(const s8v*)(kp + 32);
            f4v z = {0.f,0.f,0.f,0.f};
            f4v s = __builtin_amdgcn_mfma_f32_16x16x32_bf16(a0, bl, z, 0, 0, 0);
            s = __builtin_amdgcn_mfma_f32_16x16x32_bf16(a1, bh2, s, 0, 0, 0);
            #pragma unroll
            for (int r = 0; r < 4; ++r) {
                const int bit = nt * 16 + ar;
                if ((mw[r] >> bit) & 1u) acc[r * 2 + nt] += __expf(s[r]) * fs[r];
            }
        }
    }

    #pragma unroll
    for (int r = 0; r < 4; ++r) {
        float* ap = attn_out + ((size_t)b * SEQ + qt * 16 + aq * 4 + r) * SEQ + k0 + ar;
        #pragma unroll
        for (int nt = 0; nt < 2; ++nt) ap[nt * 16] = acc[r * 2 + nt];
    }
}

extern "C" void kernel_launch(void* const* d_in, const int* in_sizes, int n_in,
                              void* d_out, int out_size, void* d_ws, size_t ws_size,
                              hipStream_t stream) {
    const float* q_in = (const float*)d_in[0];
    const float* k_in = (const float*)d_in[1];
    const float* v_in = (const float*)d_in[2];
    const int*   mask = (const int*)d_in[3];
    const float* Wq = (const float*)d_in[4];
    const float* bq = (const float*)d_in[5];
    const float* Wk = (const float*)d_in[6];
    const float* bk = (const float*)d_in[7];
    const float* Wv = (const float*)d_in[8];
    const float* bv = (const float*)d_in[9];
    const float* Wo = (const float*)d_in[10];
    const float* bo = (const float*)d_in[11];

    float* out      = (float*)d_out;                         // [B,S,E] fp32
    float* attn_out = out + (size_t)BATCH * SEQ * EMB;       // [B,S,S] fp32

    const size_t qkv_elems = (size_t)BATCH * NH * SEQ * HD;  // 4 Mi
    uint16_t* Qb  = (uint16_t*)d_ws;                         // [B,H,S,D] bf16 (pre-scaled 1/8)
    uint16_t* Kb  = Qb + qkv_elems;                          // [B,H,S,D] bf16
    uint16_t* Vt  = Kb + qkv_elems;                          // [B,H,D,S] bf16 (transposed!)
    uint16_t* ctx = Vt + qkv_elems;                          // [B,S,E] bf16
    uint16_t* Wcb = ctx + (size_t)BATCH * SEQ * EMB;         // 4x [E,E] bf16 (8 MB)
    uint16_t* Wqb = Wcb;
    uint16_t* Wkb = Wcb + (size_t)EMB * EMB;
    uint16_t* Wvb = Wcb + 2 * (size_t)EMB * EMB;
    uint16_t* Wob = Wcb + 3 * (size_t)EMB * EMB;
    uint16_t* Xq  = Wcb + 4 * (size_t)EMB * EMB;             // [B,S,E] bf16 (8 MB)
    uint16_t* Xk  = Xq + qkv_elems;                          // [B,S,E] bf16 (8 MB)
    uint16_t* Xv  = ctx;   // alias: Xv consumed by V-proj BEFORE attn writes ctx
    uint32_t* Mb32 = (uint32_t*)(Xk + qkv_elems);            // bitpacked mask (512 KB)
    float*    linv = (float*)(Mb32 + (size_t)BATCH * SEQ * 32); // [B,H,S] 1/l (256 KB)

    // prepasses: mask bitpack + all fp32->bf16 conversions
    pack_mask<<<dim3((BATCH * SEQ * SEQ) / 256), 256, 0, stream>>>(
        mask, (unsigned long long*)Mb32);
    cvt_all<<<dim3(2048, 7), 256, 0, stream>>>(Wq, Wk, Wv, Wo, q_in, k_in, v_in,
                                               Wcb, Xq, Xk, Xv);

    // fused QKV projections: double-buffered one-barrier GEMM, one dispatch
    dim3 g3(EMB / 128, (BATCH * SEQ) / 128, 3);              // 8 x 32 x 3
    gemm3<<<g3, 512, 0, stream>>>(
        Xq, Wqb, bq, Qb, 1, 0.125f,
        Xk, Wkb, bk, Kb, 1, 1.0f,
        Xv, Wvb, bv, Vt, 2, 1.0f);

    // dual-stream flash ctx (r9 verbatim), then head-summed attn_avg
    flash_ctx<<<dim3(1024), 256, 0, stream>>>(Qb, Kb, Vt, Mb32, ctx, linv);
    attn_avg<<<dim3(SEQ / 16, BATCH * 4), 512, 0, stream>>>(Qb, Kb, Mb32, linv, attn_out);

    // O projection (same kernel, z-grid of 1)
    dim3 g1(EMB / 128, (BATCH * SEQ) / 128, 1);
    gemm3<<<g1, 512, 0, stream>>>(
        ctx, Wob, bo, out, 0, 1.0f,
        ctx, Wob, bo, out, 0, 1.0f,
        ctx, Wob, bo, out, 0, 1.0f);
}